// Round 11
// baseline (196.259 us; speedup 1.0000x reference)
//
#include <hip/hip_runtime.h>
#include <hip/hip_fp16.h>
#include <math.h>

#define HW 1024
#define EPSV 1e-5f

typedef unsigned int uint;
typedef unsigned short ushort;
typedef __attribute__((ext_vector_type(8))) short short8;
typedef __attribute__((ext_vector_type(8))) _Float16 half8;
typedef __attribute__((ext_vector_type(4))) float floatx4;

// ---------------- ws layout (float offsets), no aliasing ---------------------------
static const size_t BOFF = 0;         // 36864   fp16 Boff[tap][n32][c256]
static const size_t BD   = 36864;     // 147456  fp16 Bd[oc][tap*256+c]
static const size_t BQ   = 184320;    // 131072  bf16 Bq[par][kstep][quad][n][8] (frag order)
static const size_t XT   = 315392;    // 2097152 fp16 xT[b][p][c]
static const size_t OFFB = 2412544;   // 524288  off [b][pix][32] fp32 (atomic-accumulated)
static const size_t ST1  = 2936832;   // 1024: BN1 sum/sq, 4 striped copies of 256
static const size_t ST2  = 2937856;   // 4096: BN2 sum/sq, 16 striped copies of 256
static const size_t YP   = 2941952;   // 4194304 floats = bf16 y_part[4][pix][oc]
static const size_t YSUM = 7136256;   // 1048576 floats = bf16 ysum[pix][oc]
static const size_t YBN  = 8184832;   // 1048576 floats = bf16 ybn[pix][oc]
static const size_t OB   = 9233408;   // 4194304 floats = bf16 O[b][par][pix][oc]
// total = 13427712 floats = 53.7 MB

__device__ inline ushort f2bf(float f) {
  uint u = __builtin_bit_cast(uint, f);
  uint r = (u + 0x7FFFu + ((u >> 16) & 1u)) >> 16;
  return (ushort)r;
}
__device__ inline float b2f(ushort u) {
  return __builtin_bit_cast(float, ((uint)u) << 16);
}

// ---------------- 1. prep + xT + zero accumulators & off ---------------------------
// xT blocks pinned so image b lands on XCD b%8 (consistent with all consumers).
__global__ __launch_bounds__(256) void prep_xt_kernel(const float* __restrict__ x,
                                                      const float* __restrict__ w_off,
                                                      const float* __restrict__ w_dcn,
                                                      const float* __restrict__ w_up,
                                                      float* __restrict__ ws) {
  __shared__ float tile[64 * 65];
  int blk = blockIdx.x;
  int tid = threadIdx.x;
  if (blk < 1024) {
    // xT: x[b][c][p] fp32 -> xT[b][p][c] fp16
    int b = blk & 15, pt = (blk >> 4) & 15, cc = blk >> 8;
    int p0 = pt * 64, c0 = cc * 64;
    int pp4 = tid & 15, ci = tid >> 4;    // 16 float4-lanes x 16 rows per iter
#pragma unroll
    for (int it = 0; it < 4; ++it) {
      int c = it * 16 + ci;
      float4 v = *(const float4*)(x + ((size_t)(b * 256 + c0 + c)) * HW + p0 + pp4 * 4);
      tile[c * 65 + pp4 * 4 + 0] = v.x;
      tile[c * 65 + pp4 * 4 + 1] = v.y;
      tile[c * 65 + pp4 * 4 + 2] = v.z;
      tile[c * 65 + pp4 * 4 + 3] = v.w;
    }
    __syncthreads();
    int cp = tid & 31, pp2 = tid >> 5;
    uint* xtu = (uint*)(ws + XT);
#pragma unroll
    for (int it = 0; it < 8; ++it) {
      int p = it * 8 + pp2;
      __half2 h = __floats2half2_rn(tile[(2 * cp) * 65 + p], tile[(2 * cp + 1) * 65 + p]);
      xtu[(size_t)(b * 1024 + p0 + p) * 128 + cc * 32 + cp] = __builtin_bit_cast(uint, h);
    }
  } else if (blk < 3488) {
    int i = (blk - 1024) * 256 + tid;
    if (i < 73728) {
      // Boff[tap][n][c], zero-padded n>=27
      int c = i & 255; int n = (i >> 8) & 31; int tap = i >> 13;
      float v = (n < 27) ? w_off[((size_t)n * 256 + c) * 9 + tap] : 0.f;
      ((__half*)(ws + BOFF))[i] = __float2half(v);
    } else if (i < 73728 + 294912) {
      int d = i - 73728;            // d = oc*2304 + tap*256 + c
      int oc = d / 2304; int k = d % 2304;
      int tap = k >> 8; int c = k & 255;
      ((__half*)(ws + BD))[d] = __float2half(w_dcn[((size_t)oc * 256 + c) * 9 + tap]);
    } else if (i < 73728 + 294912 + 262144) {
      // Bq[par][kstep][quad][n][8] bf16, fragment-ordered for direct global reads
      int d = i - (73728 + 294912);
      int j = d & 7; int n = (d >> 3) & 127; int quad = (d >> 10) & 3;
      int kstep = (d >> 12) & 15; int par = d >> 16;
      int k = kstep * 32 + quad * 8 + j;
      int t4 = k >> 7; int c = k & 127;
      int ty = t4 >> 1, tx = t4 & 1;
      int pu = par >> 1, pv = par & 1;
      int ky = (1 - pu) + 2 * ty, kx = (1 - pv) + 2 * tx;
      float v = w_up[((size_t)c * 128 + n) * 16 + ky * 4 + kx];
      ((ushort*)(ws + BQ))[d] = f2bf(v);
    }
  } else {
    int i = (blk - 3488) * 256 + tid;
    if (i < 5120) ws[ST1 + i] = 0.f;           // ST1(1024)+ST2(4096)
    else if (i < 5120 + 524288) ws[OFFB + (i - 5120)] = 0.f;  // off accumulator
  }
}

// ---------------- 2. offset conv, K-split x2, atomic raw accumulate ----------------
// R0 structure (Bs LDS staging); b pinned to XCD via b = blk & 15.
__global__ __launch_bounds__(256) void offconv_mfma_kernel(const __half* __restrict__ xt,
                                                           const __half* __restrict__ boff,
                                                           float* __restrict__ off) {
  __shared__ short As[32 * 132];
  __shared__ short Bs[32 * 132];
  int blk = blockIdx.x;
  int b = blk & 15, cs = (blk >> 4) & 1, pt = blk >> 5;
  int P0 = pt * 32;
  int tid = threadIdx.x;
  int wid = tid >> 6, lane = tid & 63, lr = lane & 15, quad = lane >> 4;
  int m_w = (wid & 1) * 16, n_w = (wid >> 1) * 16;
  int arow = tid >> 3, aseg = tid & 7;  // 32 rows x 16 halves
  int pix = P0 + arow; int h = pix >> 5, w = pix & 31;

  floatx4 acc = (floatx4)0.f;

  for (int tap = 0; tap < 9; ++tap) {
    int ty = tap / 3, tx = tap % 3;
    int yy = h + ty - 1, xx = w + tx - 1;
    bool valid = (yy >= 0) && (yy < 32) && (xx >= 0) && (xx < 32);
    int pos = min(max(yy, 0), 31) * 32 + min(max(xx, 0), 31);
    const float4* ga = (const float4*)(xt + ((size_t)(b * 1024 + pos)) * 256 + cs * 128 + aseg * 16);
    float4 a0 = ga[0], a1 = ga[1];
    if (!valid) { a0 = make_float4(0.f, 0.f, 0.f, 0.f); a1 = a0; }
    const float4* gb = (const float4*)(boff + ((size_t)(tap * 32 + arow)) * 256 + cs * 128 + aseg * 16);
    float4 b0 = gb[0], b1 = gb[1];
    if (tap) __syncthreads();
    float4* qa = (float4*)(As + arow * 132 + aseg * 16);
    qa[0] = a0; qa[1] = a1;
    float4* qb = (float4*)(Bs + arow * 132 + aseg * 16);
    qb[0] = b0; qb[1] = b1;
    __syncthreads();
#pragma unroll
    for (int k2 = 0; k2 < 4; ++k2) {
      half8 af = *(const half8*)(As + (m_w + lr) * 132 + k2 * 32 + quad * 8);
      half8 bf = *(const half8*)(Bs + (n_w + lr) * 132 + k2 * 32 + quad * 8);
      acc = __builtin_amdgcn_mfma_f32_16x16x32_f16(af, bf, acc, 0, 0, 0);
    }
  }
  int n = n_w + lr;
#pragma unroll
  for (int r = 0; r < 4; ++r) {
    int m = m_w + quad * 4 + r;
    atomicAdd(&off[((size_t)(b * 1024 + P0 + m)) * 32 + n], acc[r]);
  }
}

// ---------------- 3. deformable conv: R0 structure + pinning + offset preload ------
// 64-px tiles, 4 waves (2M x 2N), B staged in LDS, 2 barriers/tap.
// b pinned to XCD via b = blk & 15; all 27 offsets preloaded before the loop.
__global__ __launch_bounds__(256) void deform_mfma_kernel(const __half* __restrict__ xt,
                                                          const float* __restrict__ off,
                                                          const float* __restrict__ b_off,
                                                          const __half* __restrict__ bd,
                                                          ushort* __restrict__ y_part) {
  __shared__ short As[64 * 72];
  __shared__ short Bs[128 * 72];
  int blk = blockIdx.x;
  int b = blk & 15;
  int rr = blk >> 4;
  int ptile = rr & 15, cs = rr >> 4;
  int tid = threadIdx.x;
  int wid = tid >> 6, lane = tid & 63, lr = lane & 15, quad = lane >> 4;
  int m_w = (wid & 1) * 32, n_w = (wid >> 1) * 64;
  int P0 = ptile * 64;
  int pix_l = tid >> 2, cseg = tid & 3;   // 64 px x 16-ch segs
  int pix = P0 + pix_l;
  int h = pix >> 5, w = pix & 31;
  const float* offb = off + (size_t)(b * 1024 + pix) * 32;
  const __half* xb = xt + (size_t)b * 1024 * 256 + cs * 64 + cseg * 16;
  int ocb = tid >> 1, seg = tid & 1;      // 128 oc x 32-ch halves
  const __half* bdr = bd + (size_t)ocb * 2304 + cs * 64 + seg * 32;

  // preload all 27 offset floats for this pixel (7 x float4 = 28)
  float4 o4[7];
#pragma unroll
  for (int i = 0; i < 7; ++i) o4[i] = ((const float4*)offb)[i];
  float oflat[28];
#pragma unroll
  for (int i = 0; i < 7; ++i) {
    oflat[4 * i] = o4[i].x; oflat[4 * i + 1] = o4[i].y;
    oflat[4 * i + 2] = o4[i].z; oflat[4 * i + 3] = o4[i].w;
  }

  floatx4 acc[2][4];
#pragma unroll
  for (int mi = 0; mi < 2; ++mi)
#pragma unroll
    for (int ni = 0; ni < 4; ++ni) acc[mi][ni] = (floatx4)0.f;

#pragma unroll
  for (int tap = 0; tap < 9; ++tap) {
    float dy = oflat[2 * tap] + b_off[2 * tap];
    float dx = oflat[2 * tap + 1] + b_off[2 * tap + 1];
    float mraw = oflat[18 + tap] + b_off[18 + tap];
    float mm = 1.f / (1.f + __expf(-mraw));
    float py = (float)(h + tap / 3 - 1) + dy;
    float px = (float)(w + tap % 3 - 1) + dx;
    float y0f = floorf(py), x0f = floorf(px);
    float wy = py - y0f, wx = px - x0f;
    int y0 = (int)y0f, x0 = (int)x0f;
    float cw[4] = {(1.f - wy) * (1.f - wx), (1.f - wy) * wx, wy * (1.f - wx), wy * wx};
    uint4 q[4][2];
    __half2 w2[4];
#pragma unroll
    for (int t = 0; t < 4; ++t) {
      int yy = y0 + (t >> 1), xx = x0 + (t & 1);
      bool v = (yy >= 0) && (yy <= 31) && (xx >= 0) && (xx <= 31);
      int yc = min(max(yy, 0), 31), xc = min(max(xx, 0), 31);
      const uint4* xr = (const uint4*)(xb + (size_t)(yc * 32 + xc) * 256);
      q[t][0] = xr[0]; q[t][1] = xr[1];
      w2[t] = __float2half2_rn(v ? cw[t] * mm : 0.f);
    }
    const float4* gb = (const float4*)(bdr + tap * 256);
    float4 b0 = gb[0], b1 = gb[1], b2 = gb[2], b3 = gb[3];

    __half2 hacc[8];
#pragma unroll
    for (int j = 0; j < 8; ++j) hacc[j] = __float2half2_rn(0.f);
#pragma unroll
    for (int t = 0; t < 4; ++t) {
      uint qa[8] = {q[t][0].x, q[t][0].y, q[t][0].z, q[t][0].w,
                    q[t][1].x, q[t][1].y, q[t][1].z, q[t][1].w};
#pragma unroll
      for (int j = 0; j < 8; ++j)
        hacc[j] = __hfma2(w2[t], __builtin_bit_cast(__half2, qa[j]), hacc[j]);
    }
    if (tap) __syncthreads();
    {
      float4 f0, f1;
      f0.x = __builtin_bit_cast(float, hacc[0]);
      f0.y = __builtin_bit_cast(float, hacc[1]);
      f0.z = __builtin_bit_cast(float, hacc[2]);
      f0.w = __builtin_bit_cast(float, hacc[3]);
      f1.x = __builtin_bit_cast(float, hacc[4]);
      f1.y = __builtin_bit_cast(float, hacc[5]);
      f1.z = __builtin_bit_cast(float, hacc[6]);
      f1.w = __builtin_bit_cast(float, hacc[7]);
      float4* qa2 = (float4*)(As + pix_l * 72 + cseg * 16);
      qa2[0] = f0; qa2[1] = f1;
    }
    float4* qb = (float4*)(Bs + ocb * 72 + seg * 32);
    qb[0] = b0; qb[1] = b1; qb[2] = b2; qb[3] = b3;
    __syncthreads();
#pragma unroll
    for (int k2 = 0; k2 < 2; ++k2) {
      half8 af[2], bf[4];
#pragma unroll
      for (int mi = 0; mi < 2; ++mi)
        af[mi] = *(const half8*)(As + (m_w + mi * 16 + lr) * 72 + k2 * 32 + quad * 8);
#pragma unroll
      for (int ni = 0; ni < 4; ++ni)
        bf[ni] = *(const half8*)(Bs + (n_w + ni * 16 + lr) * 72 + k2 * 32 + quad * 8);
#pragma unroll
      for (int mi = 0; mi < 2; ++mi)
#pragma unroll
        for (int ni = 0; ni < 4; ++ni)
          acc[mi][ni] = __builtin_amdgcn_mfma_f32_16x16x32_f16(af[mi], bf[ni], acc[mi][ni], 0, 0, 0);
    }
  }
  ushort* yp = y_part + (size_t)cs * 2097152 + ((size_t)(b * 1024 + P0)) * 128;
#pragma unroll
  for (int mi = 0; mi < 2; ++mi) {
#pragma unroll
    for (int r = 0; r < 4; ++r) {
      int m = m_w + mi * 16 + quad * 4 + r;
      ushort* orow = yp + (size_t)m * 128;
#pragma unroll
      for (int ni = 0; ni < 4; ++ni)
        orow[n_w + ni * 16 + lr] = f2bf(acc[mi][ni][r]);
    }
  }
}

// ---------------- 4. yred: vectorized, 1024 blocks, XCD-pinned, shfl stats ---------
__global__ __launch_bounds__(256) void yred_kernel(const ushort* __restrict__ yp,
                                                   const float* __restrict__ b_dcn,
                                                   ushort* __restrict__ ysum,
                                                   float* __restrict__ st1) {
  int blk = blockIdx.x;
  int b = blk & 15, seg = blk >> 4;       // 64 segs x 16 px per image
  int tid = threadIdx.x;
  int px = tid >> 4, ocg = tid & 15;      // 16 px x 16 oc-groups (8 ch each)
  int lane = tid & 63, wid = tid >> 6;
  size_t idx = ((size_t)(b * 1024 + seg * 16 + px)) * 128 + ocg * 8;
  short8 p0 = *(const short8*)(yp + idx);
  short8 p1 = *(const short8*)(yp + 2097152 + idx);
  short8 p2 = *(const short8*)(yp + 4194304 + idx);
  short8 p3 = *(const short8*)(yp + 6291456 + idx);
  float s[8], q[8];
  short8 ov;
#pragma unroll
  for (int j = 0; j < 8; ++j) {
    float v = b2f((ushort)p0[j]) + b2f((ushort)p1[j]) + b2f((ushort)p2[j])
            + b2f((ushort)p3[j]) + b_dcn[ocg * 8 + j];
    ov[j] = (short)f2bf(v);
    s[j] = v; q[j] = v * v;
  }
  *(short8*)(ysum + idx) = ov;
#pragma unroll
  for (int j = 0; j < 8; ++j) {
    s[j] += __shfl_xor(s[j], 16); s[j] += __shfl_xor(s[j], 32);
    q[j] += __shfl_xor(q[j], 16); q[j] += __shfl_xor(q[j], 32);
  }
  __shared__ float red[4][256];
  if (lane < 16) {
#pragma unroll
    for (int j = 0; j < 8; ++j) {
      red[wid][lane * 8 + j] = s[j];
      red[wid][128 + lane * 8 + j] = q[j];
    }
  }
  __syncthreads();
  float tot = red[0][tid] + red[1][tid] + red[2][tid] + red[3][tid];
  atomicAdd(&st1[(blk & 3) * 256 + tid], tot);
}

// ---------------- 5. ybn: BN1+ReLU on bf16 ysum -> bf16 ybn (XCD-pinned) -----------
__global__ __launch_bounds__(256) void ybn_kernel(const ushort* __restrict__ ysum,
                                                  const float* __restrict__ st1,
                                                  const float* __restrict__ g1,
                                                  const float* __restrict__ bt1,
                                                  ushort* __restrict__ ybn) {
  __shared__ float scs[128], shs[128];
  int tid = threadIdx.x;
  if (tid < 128) {
    float s  = st1[tid] + st1[256 + tid] + st1[512 + tid] + st1[768 + tid];
    float sq = st1[128 + tid] + st1[384 + tid] + st1[640 + tid] + st1[896 + tid];
    float mean = s / 16384.f;
    float var = sq / 16384.f - mean * mean;
    float sc = g1[tid] * rsqrtf(var + EPSV);
    scs[tid] = sc;
    shs[tid] = fmaf(-mean, sc, bt1[tid]);
  }
  __syncthreads();
  int blk = blockIdx.x;
  int b = blk & 15, seg = blk >> 4;       // pinned: 64 segs per image
  int i8 = (b * 64 + seg) * 256 + tid;
  size_t i = (size_t)i8 * 8;
  int oc = (int)(i & 127);
  uint4 pv = *(const uint4*)(ysum + i);
  uint words[4] = {pv.x, pv.y, pv.z, pv.w};
  uint owords[4];
#pragma unroll
  for (int j = 0; j < 4; ++j) {
    ushort u0 = (ushort)(words[j] & 0xFFFFu);
    ushort u1 = (ushort)(words[j] >> 16);
    int c0 = oc + 2 * j, c1 = oc + 2 * j + 1;
    float v0 = fmaxf(fmaf(b2f(u0), scs[c0], shs[c0]), 0.f);
    float v1 = fmaxf(fmaf(b2f(u1), scs[c1], shs[c1]), 0.f);
    owords[j] = (uint)f2bf(v0) | ((uint)f2bf(v1) << 16);
  }
  *(uint4*)(ybn + i) = make_uint4(owords[0], owords[1], owords[2], owords[3]);
}

// ---------------- 6. deconv: barrier-free register GEMM, 32-px blocks (2x TLP) -----
// M-split: 2048 blocks = 16 b x 4 par x 32 pt; acc[2][2], target VGPR <= 64
// so 8 blocks/CU = 32 waves/CU become resident (latency-bound, no barriers).
__global__ __launch_bounds__(256) void deconv_mfma_kernel(const ushort* __restrict__ ybn,
                                                          const ushort* __restrict__ bq,
                                                          ushort* __restrict__ O,
                                                          float* __restrict__ st2) {
  int blk = blockIdx.x;
  int b = blk & 15, par = (blk >> 4) & 3, pt = blk >> 6;   // pt in 0..31
  int pu = par >> 1, pv = par & 1;
  int tid = threadIdx.x;
  int wid = tid >> 6, lane = tid & 63, lr = lane & 15, quad = lane >> 4;
  int P0 = pt * 32;
  int hh[2], ww[2];
#pragma unroll
  for (int mi = 0; mi < 2; ++mi) {
    int p = P0 + mi * 16 + lr;
    hh[mi] = p >> 5; ww[mi] = p & 31;
  }

  floatx4 acc[2][2];
#pragma unroll
  for (int mi = 0; mi < 2; ++mi)
#pragma unroll
    for (int ni = 0; ni < 2; ++ni) acc[mi][ni] = (floatx4)0.f;

  const ushort* ybb = ybn + (size_t)b * 1024 * 128;
  const ushort* bqb = bq + par * 65536 + quad * 1024 + (wid * 32 + lr) * 8;

#pragma unroll
  for (int tap = 0; tap < 4; ++tap) {
    int ty = tap >> 1, tx = tap & 1;
    int ab[2]; bool val[2];
#pragma unroll
    for (int mi = 0; mi < 2; ++mi) {
      int i = hh[mi] + pu - ty, j = ww[mi] + pv - tx;
      val[mi] = (i >= 0) && (i <= 31) && (j >= 0) && (j <= 31);
      int pos = min(max(i, 0), 31) * 32 + min(max(j, 0), 31);
      ab[mi] = pos * 128;
    }
#pragma unroll
    for (int k2 = 0; k2 < 4; ++k2) {
      int kstep = tap * 4 + k2;
      int c0 = k2 * 32 + quad * 8;
      short8 bf[2];
#pragma unroll
      for (int ni = 0; ni < 2; ++ni)
        bf[ni] = *(const short8*)(bqb + kstep * 4096 + ni * 128);
      short8 af[2];
#pragma unroll
      for (int mi = 0; mi < 2; ++mi) {
        short8 a = *(const short8*)(ybb + ab[mi] + c0);
        af[mi] = val[mi] ? a : (short8)0;
      }
#pragma unroll
      for (int mi = 0; mi < 2; ++mi)
#pragma unroll
        for (int ni = 0; ni < 2; ++ni)
          acc[mi][ni] = __builtin_amdgcn_mfma_f32_16x16x32_bf16(af[mi], bf[ni], acc[mi][ni], 0, 0, 0);
    }
  }
  size_t obase = (size_t)(b * 4 + par) * 1024 * 128;
#pragma unroll
  for (int mi = 0; mi < 2; ++mi) {
#pragma unroll
    for (int r = 0; r < 4; ++r) {
      int m = mi * 16 + quad * 4 + r;
      ushort* orow = O + obase + (size_t)(P0 + m) * 128 + wid * 32;
#pragma unroll
      for (int ni = 0; ni < 2; ++ni)
        orow[ni * 16 + lr] = f2bf(acc[mi][ni][r]);
    }
  }
  float sn[2], qn[2];
#pragma unroll
  for (int ni = 0; ni < 2; ++ni) {
    float s = 0.f, q = 0.f;
#pragma unroll
    for (int mi = 0; mi < 2; ++mi)
#pragma unroll
      for (int r = 0; r < 4; ++r) {
        float v = acc[mi][ni][r];
        s += v; q = fmaf(v, v, q);
      }
    sn[ni] = s; qn[ni] = q;
  }
#pragma unroll
  for (int ni = 0; ni < 2; ++ni) {
    sn[ni] += __shfl_xor(sn[ni], 16);
    sn[ni] += __shfl_xor(sn[ni], 32);
    qn[ni] += __shfl_xor(qn[ni], 16);
    qn[ni] += __shfl_xor(qn[ni], 32);
  }
  if (lane < 16) {
    float* dst = st2 + (pt & 15) * 256;
#pragma unroll
    for (int ni = 0; ni < 2; ++ni) {
      atomicAdd(&dst[wid * 32 + ni * 16 + lr], sn[ni]);
      atomicAdd(&dst[128 + wid * 32 + ni * 16 + lr], qn[ni]);
    }
  }
}

// ---------------- 7. bnout: BN2 + transpose, full-row coalesced stores -------------
// Block = (b, pu, uu): both pv phases -> contiguous float4 out rows.
__global__ __launch_bounds__(256) void bnout_kernel(const ushort* __restrict__ O,
                                                    const float* __restrict__ st2,
                                                    const float* __restrict__ g2,
                                                    const float* __restrict__ bt2,
                                                    float* __restrict__ out) {
  __shared__ float tile[128 * 65];   // 33.3 KB
  __shared__ float scs[128], shs[128];
  int blk = blockIdx.x;
  int b = blk & 15, pu = (blk >> 4) & 1, uu = blk >> 5;   // 16 x 2 x 32 = 1024
  int tid = threadIdx.x;
  if (tid < 128) {
    float s = 0.f, sq = 0.f;
#pragma unroll
    for (int c = 0; c < 16; ++c) {
      s += st2[c * 256 + tid];
      sq += st2[c * 256 + 128 + tid];
    }
    float mean = s / 65536.f;
    float var = sq / 65536.f - mean * mean;
    float sc = g2[tid] * rsqrtf(var + EPSV);
    scs[tid] = sc;
    shs[tid] = fmaf(-mean, sc, bt2[tid]);
  }
  __syncthreads();
  // load both pv slices: 2 x 32 vv x 128 oc, uint2 (4 oc) per thread per iter
#pragma unroll
  for (int it = 0; it < 8; ++it) {
    int linear = it * 256 + tid;          // 0..2047
    int ocg = linear & 31;                 // 4-oc group
    int vv = (linear >> 5) & 31;
    int pv = linear >> 10;                 // 0..1
    const ushort* src = O + ((size_t)(b * 4 + 2 * pu + pv) * 1024 + uu * 32 + vv) * 128 + ocg * 4;
    uint2 u = *(const uint2*)src;
    int col = 2 * vv + pv;
    int oc0 = ocg * 4;
    ushort e0 = (ushort)(u.x & 0xFFFFu), e1 = (ushort)(u.x >> 16);
    ushort e2 = (ushort)(u.y & 0xFFFFu), e3 = (ushort)(u.y >> 16);
    tile[(oc0 + 0) * 65 + col] = fmaxf(fmaf(b2f(e0), scs[oc0 + 0], shs[oc0 + 0]), 0.f);
    tile[(oc0 + 1) * 65 + col] = fmaxf(fmaf(b2f(e1), scs[oc0 + 1], shs[oc0 + 1]), 0.f);
    tile[(oc0 + 2) * 65 + col] = fmaxf(fmaf(b2f(e2), scs[oc0 + 2], shs[oc0 + 2]), 0.f);
    tile[(oc0 + 3) * 65 + col] = fmaxf(fmaf(b2f(e3), scs[oc0 + 3], shs[oc0 + 3]), 0.f);
  }
  __syncthreads();
  // store: full contiguous out rows, float4 per thread; 8 iters cover oc 0..127
  int row = 2 * uu + pu;
#pragma unroll
  for (int it = 0; it < 8; ++it) {
    int oc = it * 16 + (tid >> 4);
    int c4 = (tid & 15) * 4;
    float4 v;
    v.x = tile[oc * 65 + c4 + 0];
    v.y = tile[oc * 65 + c4 + 1];
    v.z = tile[oc * 65 + c4 + 2];
    v.w = tile[oc * 65 + c4 + 3];
    *(float4*)(out + ((size_t)(b * 128 + oc)) * 4096 + row * 64 + c4) = v;
  }
}

extern "C" void kernel_launch(void* const* d_in, const int* in_sizes, int n_in,
                              void* d_out, int out_size, void* d_ws, size_t ws_size,
                              hipStream_t stream) {
  const float* x     = (const float*)d_in[0];
  const float* w_off = (const float*)d_in[1];
  const float* b_off = (const float*)d_in[2];
  const float* w_dcn = (const float*)d_in[3];
  const float* b_dcn = (const float*)d_in[4];
  const float* g1    = (const float*)d_in[5];
  const float* bt1   = (const float*)d_in[6];
  const float* w_up  = (const float*)d_in[7];
  const float* g2    = (const float*)d_in[8];
  const float* bt2   = (const float*)d_in[9];
  float* ws  = (float*)d_ws;
  float* out = (float*)d_out;

  prep_xt_kernel<<<5556, 256, 0, stream>>>(x, w_off, w_dcn, w_up, ws);
  offconv_mfma_kernel<<<1024, 256, 0, stream>>>((const __half*)(ws + XT),
                                                (const __half*)(ws + BOFF), ws + OFFB);
  deform_mfma_kernel<<<1024, 256, 0, stream>>>((const __half*)(ws + XT), ws + OFFB, b_off,
                                               (const __half*)(ws + BD), (ushort*)(ws + YP));
  yred_kernel<<<1024, 256, 0, stream>>>((const ushort*)(ws + YP), b_dcn,
                                        (ushort*)(ws + YSUM), ws + ST1);
  ybn_kernel<<<1024, 256, 0, stream>>>((const ushort*)(ws + YSUM), ws + ST1, g1, bt1,
                                       (ushort*)(ws + YBN));
  deconv_mfma_kernel<<<2048, 256, 0, stream>>>((const ushort*)(ws + YBN),
                                               (const ushort*)(ws + BQ),
                                               (ushort*)(ws + OB), ws + ST2);
  bnout_kernel<<<1024, 256, 0, stream>>>((const ushort*)(ws + OB), ws + ST2, g2, bt2, out);
}

// Round 13
// 169.262 us; speedup vs baseline: 1.1595x; 1.1595x over previous
//
#include <hip/hip_runtime.h>
#include <hip/hip_fp16.h>
#include <math.h>

#define HW 1024
#define EPSV 1e-5f

typedef unsigned int uint;
typedef unsigned short ushort;
typedef __attribute__((ext_vector_type(8))) short short8;
typedef __attribute__((ext_vector_type(8))) _Float16 half8;
typedef __attribute__((ext_vector_type(4))) float floatx4;

// ---------------- ws layout (float offsets), no aliasing ---------------------------
static const size_t BOFF = 0;         // 36864   fp16 Boff[tap][n32][c256]
static const size_t BD   = 36864;     // 147456  fp16 Bd[oc][tap*256+c]
static const size_t BQ   = 184320;    // 131072  bf16 Bq[par][kstep][quad][n][8] (frag order)
static const size_t XT   = 315392;    // 2097152 fp16 xT[b][p][c]
static const size_t OFFB = 2412544;   // 524288  off [b][pix][32] fp32 (atomic-accumulated)
static const size_t ST1  = 2936832;   // 1024: BN1 sum/sq, 4 striped copies of 256
static const size_t ST2  = 2937856;   // 4096: BN2 sum/sq, 16 striped copies of 256
static const size_t YP   = 2941952;   // 4194304 floats = bf16 y_part[4][pix][oc]
static const size_t YSUM = 7136256;   // 1048576 floats = bf16 ysum[pix][oc]
static const size_t YBN  = 8184832;   // 1048576 floats = bf16 ybn[pix][oc]
static const size_t OB   = 9233408;   // 4194304 floats = bf16 O[b][par][pix][oc]
// total = 13427712 floats = 53.7 MB

__device__ inline ushort f2bf(float f) {
  uint u = __builtin_bit_cast(uint, f);
  uint r = (u + 0x7FFFu + ((u >> 16) & 1u)) >> 16;
  return (ushort)r;
}
__device__ inline float b2f(ushort u) {
  return __builtin_bit_cast(float, ((uint)u) << 16);
}

// ---------------- 1. prep + xT + zero accumulators & off ---------------------------
// xT blocks pinned so image b lands on XCD b%8 (consistent with all consumers).
__global__ __launch_bounds__(256) void prep_xt_kernel(const float* __restrict__ x,
                                                      const float* __restrict__ w_off,
                                                      const float* __restrict__ w_dcn,
                                                      const float* __restrict__ w_up,
                                                      float* __restrict__ ws) {
  __shared__ float tile[64 * 65];
  int blk = blockIdx.x;
  int tid = threadIdx.x;
  if (blk < 1024) {
    // xT: x[b][c][p] fp32 -> xT[b][p][c] fp16
    int b = blk & 15, pt = (blk >> 4) & 15, cc = blk >> 8;
    int p0 = pt * 64, c0 = cc * 64;
    int pp4 = tid & 15, ci = tid >> 4;    // 16 float4-lanes x 16 rows per iter
#pragma unroll
    for (int it = 0; it < 4; ++it) {
      int c = it * 16 + ci;
      float4 v = *(const float4*)(x + ((size_t)(b * 256 + c0 + c)) * HW + p0 + pp4 * 4);
      tile[c * 65 + pp4 * 4 + 0] = v.x;
      tile[c * 65 + pp4 * 4 + 1] = v.y;
      tile[c * 65 + pp4 * 4 + 2] = v.z;
      tile[c * 65 + pp4 * 4 + 3] = v.w;
    }
    __syncthreads();
    int cp = tid & 31, pp2 = tid >> 5;
    uint* xtu = (uint*)(ws + XT);
#pragma unroll
    for (int it = 0; it < 8; ++it) {
      int p = it * 8 + pp2;
      __half2 h = __floats2half2_rn(tile[(2 * cp) * 65 + p], tile[(2 * cp + 1) * 65 + p]);
      xtu[(size_t)(b * 1024 + p0 + p) * 128 + cc * 32 + cp] = __builtin_bit_cast(uint, h);
    }
  } else if (blk < 3488) {
    int i = (blk - 1024) * 256 + tid;
    if (i < 73728) {
      // Boff[tap][n][c], zero-padded n>=27
      int c = i & 255; int n = (i >> 8) & 31; int tap = i >> 13;
      float v = (n < 27) ? w_off[((size_t)n * 256 + c) * 9 + tap] : 0.f;
      ((__half*)(ws + BOFF))[i] = __float2half(v);
    } else if (i < 73728 + 294912) {
      int d = i - 73728;            // d = oc*2304 + tap*256 + c
      int oc = d / 2304; int k = d % 2304;
      int tap = k >> 8; int c = k & 255;
      ((__half*)(ws + BD))[d] = __float2half(w_dcn[((size_t)oc * 256 + c) * 9 + tap]);
    } else if (i < 73728 + 294912 + 262144) {
      // Bq[par][kstep][quad][n][8] bf16, fragment-ordered for direct global reads
      int d = i - (73728 + 294912);
      int j = d & 7; int n = (d >> 3) & 127; int quad = (d >> 10) & 3;
      int kstep = (d >> 12) & 15; int par = d >> 16;
      int k = kstep * 32 + quad * 8 + j;
      int t4 = k >> 7; int c = k & 127;
      int ty = t4 >> 1, tx = t4 & 1;
      int pu = par >> 1, pv = par & 1;
      int ky = (1 - pu) + 2 * ty, kx = (1 - pv) + 2 * tx;
      float v = w_up[((size_t)c * 128 + n) * 16 + ky * 4 + kx];
      ((ushort*)(ws + BQ))[d] = f2bf(v);
    }
  } else {
    int i = (blk - 3488) * 256 + tid;
    if (i < 5120) ws[ST1 + i] = 0.f;           // ST1(1024)+ST2(4096)
    else if (i < 5120 + 524288) ws[OFFB + (i - 5120)] = 0.f;  // off accumulator
  }
}

// ---------------- 2. offset conv, K-split x2, atomic raw accumulate ----------------
// R0 structure (Bs LDS staging); b pinned to XCD via b = blk & 15.
__global__ __launch_bounds__(256) void offconv_mfma_kernel(const __half* __restrict__ xt,
                                                           const __half* __restrict__ boff,
                                                           float* __restrict__ off) {
  __shared__ short As[32 * 132];
  __shared__ short Bs[32 * 132];
  int blk = blockIdx.x;
  int b = blk & 15, cs = (blk >> 4) & 1, pt = blk >> 5;
  int P0 = pt * 32;
  int tid = threadIdx.x;
  int wid = tid >> 6, lane = tid & 63, lr = lane & 15, quad = lane >> 4;
  int m_w = (wid & 1) * 16, n_w = (wid >> 1) * 16;
  int arow = tid >> 3, aseg = tid & 7;  // 32 rows x 16 halves
  int pix = P0 + arow; int h = pix >> 5, w = pix & 31;

  floatx4 acc = (floatx4)0.f;

  for (int tap = 0; tap < 9; ++tap) {
    int ty = tap / 3, tx = tap % 3;
    int yy = h + ty - 1, xx = w + tx - 1;
    bool valid = (yy >= 0) && (yy < 32) && (xx >= 0) && (xx < 32);
    int pos = min(max(yy, 0), 31) * 32 + min(max(xx, 0), 31);
    const float4* ga = (const float4*)(xt + ((size_t)(b * 1024 + pos)) * 256 + cs * 128 + aseg * 16);
    float4 a0 = ga[0], a1 = ga[1];
    if (!valid) { a0 = make_float4(0.f, 0.f, 0.f, 0.f); a1 = a0; }
    const float4* gb = (const float4*)(boff + ((size_t)(tap * 32 + arow)) * 256 + cs * 128 + aseg * 16);
    float4 b0 = gb[0], b1 = gb[1];
    if (tap) __syncthreads();
    float4* qa = (float4*)(As + arow * 132 + aseg * 16);
    qa[0] = a0; qa[1] = a1;
    float4* qb = (float4*)(Bs + arow * 132 + aseg * 16);
    qb[0] = b0; qb[1] = b1;
    __syncthreads();
#pragma unroll
    for (int k2 = 0; k2 < 4; ++k2) {
      half8 af = *(const half8*)(As + (m_w + lr) * 132 + k2 * 32 + quad * 8);
      half8 bf = *(const half8*)(Bs + (n_w + lr) * 132 + k2 * 32 + quad * 8);
      acc = __builtin_amdgcn_mfma_f32_16x16x32_f16(af, bf, acc, 0, 0, 0);
    }
  }
  int n = n_w + lr;
#pragma unroll
  for (int r = 0; r < 4; ++r) {
    int m = m_w + quad * 4 + r;
    atomicAdd(&off[((size_t)(b * 1024 + P0 + m)) * 32 + n], acc[r]);
  }
}

// ---------------- 3. deformable conv: R0 structure + pinning + offset preload ------
// 64-px tiles, 4 waves (2M x 2N), B staged in LDS, 2 barriers/tap.
// b pinned to XCD via b = blk & 15; all 27 offsets preloaded before the loop.
__global__ __launch_bounds__(256) void deform_mfma_kernel(const __half* __restrict__ xt,
                                                          const float* __restrict__ off,
                                                          const float* __restrict__ b_off,
                                                          const __half* __restrict__ bd,
                                                          ushort* __restrict__ y_part) {
  __shared__ short As[64 * 72];
  __shared__ short Bs[128 * 72];
  int blk = blockIdx.x;
  int b = blk & 15;
  int rr = blk >> 4;
  int ptile = rr & 15, cs = rr >> 4;
  int tid = threadIdx.x;
  int wid = tid >> 6, lane = tid & 63, lr = lane & 15, quad = lane >> 4;
  int m_w = (wid & 1) * 32, n_w = (wid >> 1) * 64;
  int P0 = ptile * 64;
  int pix_l = tid >> 2, cseg = tid & 3;   // 64 px x 16-ch segs
  int pix = P0 + pix_l;
  int h = pix >> 5, w = pix & 31;
  const float* offb = off + (size_t)(b * 1024 + pix) * 32;
  const __half* xb = xt + (size_t)b * 1024 * 256 + cs * 64 + cseg * 16;
  int ocb = tid >> 1, seg = tid & 1;      // 128 oc x 32-ch halves
  const __half* bdr = bd + (size_t)ocb * 2304 + cs * 64 + seg * 32;

  // preload all 27 offset floats for this pixel (7 x float4 = 28)
  float4 o4[7];
#pragma unroll
  for (int i = 0; i < 7; ++i) o4[i] = ((const float4*)offb)[i];
  float oflat[28];
#pragma unroll
  for (int i = 0; i < 7; ++i) {
    oflat[4 * i] = o4[i].x; oflat[4 * i + 1] = o4[i].y;
    oflat[4 * i + 2] = o4[i].z; oflat[4 * i + 3] = o4[i].w;
  }

  floatx4 acc[2][4];
#pragma unroll
  for (int mi = 0; mi < 2; ++mi)
#pragma unroll
    for (int ni = 0; ni < 4; ++ni) acc[mi][ni] = (floatx4)0.f;

#pragma unroll
  for (int tap = 0; tap < 9; ++tap) {
    float dy = oflat[2 * tap] + b_off[2 * tap];
    float dx = oflat[2 * tap + 1] + b_off[2 * tap + 1];
    float mraw = oflat[18 + tap] + b_off[18 + tap];
    float mm = 1.f / (1.f + __expf(-mraw));
    float py = (float)(h + tap / 3 - 1) + dy;
    float px = (float)(w + tap % 3 - 1) + dx;
    float y0f = floorf(py), x0f = floorf(px);
    float wy = py - y0f, wx = px - x0f;
    int y0 = (int)y0f, x0 = (int)x0f;
    float cw[4] = {(1.f - wy) * (1.f - wx), (1.f - wy) * wx, wy * (1.f - wx), wy * wx};
    uint4 q[4][2];
    __half2 w2[4];
#pragma unroll
    for (int t = 0; t < 4; ++t) {
      int yy = y0 + (t >> 1), xx = x0 + (t & 1);
      bool v = (yy >= 0) && (yy <= 31) && (xx >= 0) && (xx <= 31);
      int yc = min(max(yy, 0), 31), xc = min(max(xx, 0), 31);
      const uint4* xr = (const uint4*)(xb + (size_t)(yc * 32 + xc) * 256);
      q[t][0] = xr[0]; q[t][1] = xr[1];
      w2[t] = __float2half2_rn(v ? cw[t] * mm : 0.f);
    }
    const float4* gb = (const float4*)(bdr + tap * 256);
    float4 b0 = gb[0], b1 = gb[1], b2 = gb[2], b3 = gb[3];

    __half2 hacc[8];
#pragma unroll
    for (int j = 0; j < 8; ++j) hacc[j] = __float2half2_rn(0.f);
#pragma unroll
    for (int t = 0; t < 4; ++t) {
      uint qa[8] = {q[t][0].x, q[t][0].y, q[t][0].z, q[t][0].w,
                    q[t][1].x, q[t][1].y, q[t][1].z, q[t][1].w};
#pragma unroll
      for (int j = 0; j < 8; ++j)
        hacc[j] = __hfma2(w2[t], __builtin_bit_cast(__half2, qa[j]), hacc[j]);
    }
    if (tap) __syncthreads();
    {
      float4 f0, f1;
      f0.x = __builtin_bit_cast(float, hacc[0]);
      f0.y = __builtin_bit_cast(float, hacc[1]);
      f0.z = __builtin_bit_cast(float, hacc[2]);
      f0.w = __builtin_bit_cast(float, hacc[3]);
      f1.x = __builtin_bit_cast(float, hacc[4]);
      f1.y = __builtin_bit_cast(float, hacc[5]);
      f1.z = __builtin_bit_cast(float, hacc[6]);
      f1.w = __builtin_bit_cast(float, hacc[7]);
      float4* qa2 = (float4*)(As + pix_l * 72 + cseg * 16);
      qa2[0] = f0; qa2[1] = f1;
    }
    float4* qb = (float4*)(Bs + ocb * 72 + seg * 32);
    qb[0] = b0; qb[1] = b1; qb[2] = b2; qb[3] = b3;
    __syncthreads();
#pragma unroll
    for (int k2 = 0; k2 < 2; ++k2) {
      half8 af[2], bf[4];
#pragma unroll
      for (int mi = 0; mi < 2; ++mi)
        af[mi] = *(const half8*)(As + (m_w + mi * 16 + lr) * 72 + k2 * 32 + quad * 8);
#pragma unroll
      for (int ni = 0; ni < 4; ++ni)
        bf[ni] = *(const half8*)(Bs + (n_w + ni * 16 + lr) * 72 + k2 * 32 + quad * 8);
#pragma unroll
      for (int mi = 0; mi < 2; ++mi)
#pragma unroll
        for (int ni = 0; ni < 4; ++ni)
          acc[mi][ni] = __builtin_amdgcn_mfma_f32_16x16x32_f16(af[mi], bf[ni], acc[mi][ni], 0, 0, 0);
    }
  }
  ushort* yp = y_part + (size_t)cs * 2097152 + ((size_t)(b * 1024 + P0)) * 128;
#pragma unroll
  for (int mi = 0; mi < 2; ++mi) {
#pragma unroll
    for (int r = 0; r < 4; ++r) {
      int m = m_w + mi * 16 + quad * 4 + r;
      ushort* orow = yp + (size_t)m * 128;
#pragma unroll
      for (int ni = 0; ni < 4; ++ni)
        orow[n_w + ni * 16 + lr] = f2bf(acc[mi][ni][r]);
    }
  }
}

// ---------------- 4. yred: vectorized, 1024 blocks, XCD-pinned, shfl stats ---------
__global__ __launch_bounds__(256) void yred_kernel(const ushort* __restrict__ yp,
                                                   const float* __restrict__ b_dcn,
                                                   ushort* __restrict__ ysum,
                                                   float* __restrict__ st1) {
  int blk = blockIdx.x;
  int b = blk & 15, seg = blk >> 4;       // 64 segs x 16 px per image
  int tid = threadIdx.x;
  int px = tid >> 4, ocg = tid & 15;      // 16 px x 16 oc-groups (8 ch each)
  int lane = tid & 63, wid = tid >> 6;
  size_t idx = ((size_t)(b * 1024 + seg * 16 + px)) * 128 + ocg * 8;
  short8 p0 = *(const short8*)(yp + idx);
  short8 p1 = *(const short8*)(yp + 2097152 + idx);
  short8 p2 = *(const short8*)(yp + 4194304 + idx);
  short8 p3 = *(const short8*)(yp + 6291456 + idx);
  float s[8], q[8];
  short8 ov;
#pragma unroll
  for (int j = 0; j < 8; ++j) {
    float v = b2f((ushort)p0[j]) + b2f((ushort)p1[j]) + b2f((ushort)p2[j])
            + b2f((ushort)p3[j]) + b_dcn[ocg * 8 + j];
    ov[j] = (short)f2bf(v);
    s[j] = v; q[j] = v * v;
  }
  *(short8*)(ysum + idx) = ov;
#pragma unroll
  for (int j = 0; j < 8; ++j) {
    s[j] += __shfl_xor(s[j], 16); s[j] += __shfl_xor(s[j], 32);
    q[j] += __shfl_xor(q[j], 16); q[j] += __shfl_xor(q[j], 32);
  }
  __shared__ float red[4][256];
  if (lane < 16) {
#pragma unroll
    for (int j = 0; j < 8; ++j) {
      red[wid][lane * 8 + j] = s[j];
      red[wid][128 + lane * 8 + j] = q[j];
    }
  }
  __syncthreads();
  float tot = red[0][tid] + red[1][tid] + red[2][tid] + red[3][tid];
  atomicAdd(&st1[(blk & 3) * 256 + tid], tot);
}

// ---------------- 5. ybn: BN1+ReLU on bf16 ysum -> bf16 ybn (XCD-pinned) -----------
__global__ __launch_bounds__(256) void ybn_kernel(const ushort* __restrict__ ysum,
                                                  const float* __restrict__ st1,
                                                  const float* __restrict__ g1,
                                                  const float* __restrict__ bt1,
                                                  ushort* __restrict__ ybn) {
  __shared__ float scs[128], shs[128];
  int tid = threadIdx.x;
  if (tid < 128) {
    float s  = st1[tid] + st1[256 + tid] + st1[512 + tid] + st1[768 + tid];
    float sq = st1[128 + tid] + st1[384 + tid] + st1[640 + tid] + st1[896 + tid];
    float mean = s / 16384.f;
    float var = sq / 16384.f - mean * mean;
    float sc = g1[tid] * rsqrtf(var + EPSV);
    scs[tid] = sc;
    shs[tid] = fmaf(-mean, sc, bt1[tid]);
  }
  __syncthreads();
  int blk = blockIdx.x;
  int b = blk & 15, seg = blk >> 4;       // pinned: 64 segs per image
  int i8 = (b * 64 + seg) * 256 + tid;
  size_t i = (size_t)i8 * 8;
  int oc = (int)(i & 127);
  uint4 pv = *(const uint4*)(ysum + i);
  uint words[4] = {pv.x, pv.y, pv.z, pv.w};
  uint owords[4];
#pragma unroll
  for (int j = 0; j < 4; ++j) {
    ushort u0 = (ushort)(words[j] & 0xFFFFu);
    ushort u1 = (ushort)(words[j] >> 16);
    int c0 = oc + 2 * j, c1 = oc + 2 * j + 1;
    float v0 = fmaxf(fmaf(b2f(u0), scs[c0], shs[c0]), 0.f);
    float v1 = fmaxf(fmaf(b2f(u1), scs[c1], shs[c1]), 0.f);
    owords[j] = (uint)f2bf(v0) | ((uint)f2bf(v1) << 16);
  }
  *(uint4*)(ybn + i) = make_uint4(owords[0], owords[1], owords[2], owords[3]);
}

// ---------------- 6. deconv: LDS-staged A (3 rows x 34 cols x 128ch), 1 barrier ----
// Fix for scattered-ybn gathers (R11 diag: occupancy 41% but MfmaUtil 7% ->
// L2 request-rate bound). Stage block footprint coalesced once; af from LDS.
__global__ __launch_bounds__(256) void deconv_mfma_kernel(const ushort* __restrict__ ybn,
                                                          const ushort* __restrict__ bq,
                                                          ushort* __restrict__ O,
                                                          float* __restrict__ st2) {
  __shared__ short Asd[102 * 132];   // 26.9 KB: [r*34+jj][132], 128 ch used + pad
  int blk = blockIdx.x;
  int b = blk & 15, par = (blk >> 4) & 3, pt = blk >> 6;   // pt 0..15
  int pu = par >> 1, pv = par & 1;
  int tid = threadIdx.x;
  int wid = tid >> 6, lane = tid & 63, lr = lane & 15, quad = lane >> 4;
  int P0 = pt * 64;
  int h0 = pt * 2;
  const ushort* ybb = ybn + (size_t)b * 1024 * 128;

  // stage 3 rows x 34 w-positions x 128 ch, clamped, fully coalesced (16B/lane)
  for (int idx = tid; idx < 1632; idx += 256) {
    int pos = idx >> 4, seg = idx & 15;
    int r = pos / 34, jj = pos - r * 34;
    int ig = min(max(h0 + pu - 1 + r, 0), 31);
    int jg = min(max(pv - 1 + jj, 0), 31);
    const float4* src = (const float4*)(ybb + (size_t)(ig * 32 + jg) * 128 + seg * 8);
    *(float4*)(Asd + pos * 132 + seg * 8) = *src;
  }
  __syncthreads();

  int hh[4], ww[4];
#pragma unroll
  for (int mi = 0; mi < 4; ++mi) {
    int p = P0 + mi * 16 + lr;
    hh[mi] = p >> 5; ww[mi] = p & 31;
  }

  floatx4 acc[4][2];
#pragma unroll
  for (int mi = 0; mi < 4; ++mi)
#pragma unroll
    for (int ni = 0; ni < 2; ++ni) acc[mi][ni] = (floatx4)0.f;

  const ushort* bqb = bq + par * 65536 + quad * 1024 + (wid * 32 + lr) * 8;

#pragma unroll
  for (int tap = 0; tap < 4; ++tap) {
    int ty = tap >> 1, tx = tap & 1;
    int apos[4]; bool val[4];
#pragma unroll
    for (int mi = 0; mi < 4; ++mi) {
      int i = hh[mi] + pu - ty, j = ww[mi] + pv - tx;
      val[mi] = (i >= 0) && (i <= 31) && (j >= 0) && (j <= 31);
      int r = hh[mi] - h0 + 1 - ty;        // 0..2
      int jdx = ww[mi] - tx + 1;           // 0..33
      apos[mi] = (r * 34 + jdx) * 132;
    }
#pragma unroll
    for (int k2 = 0; k2 < 4; ++k2) {
      int kstep = tap * 4 + k2;
      int c0 = k2 * 32 + quad * 8;
      short8 bf[2];
#pragma unroll
      for (int ni = 0; ni < 2; ++ni)
        bf[ni] = *(const short8*)(bqb + kstep * 4096 + ni * 128);
      short8 af[4];
#pragma unroll
      for (int mi = 0; mi < 4; ++mi) {
        short8 a = *(const short8*)(Asd + apos[mi] + c0);
        af[mi] = val[mi] ? a : (short8)0;
      }
#pragma unroll
      for (int mi = 0; mi < 4; ++mi)
#pragma unroll
        for (int ni = 0; ni < 2; ++ni)
          acc[mi][ni] = __builtin_amdgcn_mfma_f32_16x16x32_bf16(af[mi], bf[ni], acc[mi][ni], 0, 0, 0);
    }
  }
  size_t obase = (size_t)(b * 4 + par) * 1024 * 128;
#pragma unroll
  for (int mi = 0; mi < 4; ++mi) {
#pragma unroll
    for (int r = 0; r < 4; ++r) {
      int m = mi * 16 + quad * 4 + r;
      ushort* orow = O + obase + (size_t)(P0 + m) * 128 + wid * 32;
#pragma unroll
      for (int ni = 0; ni < 2; ++ni)
        orow[ni * 16 + lr] = f2bf(acc[mi][ni][r]);
    }
  }
  float sn[2], qn[2];
#pragma unroll
  for (int ni = 0; ni < 2; ++ni) {
    float s = 0.f, q = 0.f;
#pragma unroll
    for (int mi = 0; mi < 4; ++mi)
#pragma unroll
      for (int r = 0; r < 4; ++r) {
        float v = acc[mi][ni][r];
        s += v; q = fmaf(v, v, q);
      }
    sn[ni] = s; qn[ni] = q;
  }
#pragma unroll
  for (int ni = 0; ni < 2; ++ni) {
    sn[ni] += __shfl_xor(sn[ni], 16);
    sn[ni] += __shfl_xor(sn[ni], 32);
    qn[ni] += __shfl_xor(qn[ni], 16);
    qn[ni] += __shfl_xor(qn[ni], 32);
  }
  if (lane < 16) {
    float* dst = st2 + pt * 256;
#pragma unroll
    for (int ni = 0; ni < 2; ++ni) {
      atomicAdd(&dst[wid * 32 + ni * 16 + lr], sn[ni]);
      atomicAdd(&dst[128 + wid * 32 + ni * 16 + lr], qn[ni]);
    }
  }
}

// ---------------- 7. bnout: BN2 + transpose, full-row coalesced stores -------------
// Block = (b, pu, uu): both pv phases -> contiguous float4 out rows.
__global__ __launch_bounds__(256) void bnout_kernel(const ushort* __restrict__ O,
                                                    const float* __restrict__ st2,
                                                    const float* __restrict__ g2,
                                                    const float* __restrict__ bt2,
                                                    float* __restrict__ out) {
  __shared__ float tile[128 * 65];   // 33.3 KB
  __shared__ float scs[128], shs[128];
  int blk = blockIdx.x;
  int b = blk & 15, pu = (blk >> 4) & 1, uu = blk >> 5;   // 16 x 2 x 32 = 1024
  int tid = threadIdx.x;
  if (tid < 128) {
    float s = 0.f, sq = 0.f;
#pragma unroll
    for (int c = 0; c < 16; ++c) {
      s += st2[c * 256 + tid];
      sq += st2[c * 256 + 128 + tid];
    }
    float mean = s / 65536.f;
    float var = sq / 65536.f - mean * mean;
    float sc = g2[tid] * rsqrtf(var + EPSV);
    scs[tid] = sc;
    shs[tid] = fmaf(-mean, sc, bt2[tid]);
  }
  __syncthreads();
  // load both pv slices: 2 x 32 vv x 128 oc, uint2 (4 oc) per thread per iter
#pragma unroll
  for (int it = 0; it < 8; ++it) {
    int linear = it * 256 + tid;          // 0..2047
    int ocg = linear & 31;                 // 4-oc group
    int vv = (linear >> 5) & 31;
    int pv = linear >> 10;                 // 0..1
    const ushort* src = O + ((size_t)(b * 4 + 2 * pu + pv) * 1024 + uu * 32 + vv) * 128 + ocg * 4;
    uint2 u = *(const uint2*)src;
    int col = 2 * vv + pv;
    int oc0 = ocg * 4;
    ushort e0 = (ushort)(u.x & 0xFFFFu), e1 = (ushort)(u.x >> 16);
    ushort e2 = (ushort)(u.y & 0xFFFFu), e3 = (ushort)(u.y >> 16);
    tile[(oc0 + 0) * 65 + col] = fmaxf(fmaf(b2f(e0), scs[oc0 + 0], shs[oc0 + 0]), 0.f);
    tile[(oc0 + 1) * 65 + col] = fmaxf(fmaf(b2f(e1), scs[oc0 + 1], shs[oc0 + 1]), 0.f);
    tile[(oc0 + 2) * 65 + col] = fmaxf(fmaf(b2f(e2), scs[oc0 + 2], shs[oc0 + 2]), 0.f);
    tile[(oc0 + 3) * 65 + col] = fmaxf(fmaf(b2f(e3), scs[oc0 + 3], shs[oc0 + 3]), 0.f);
  }
  __syncthreads();
  // store: full contiguous out rows, float4 per thread; 8 iters cover oc 0..127
  int row = 2 * uu + pu;
#pragma unroll
  for (int it = 0; it < 8; ++it) {
    int oc = it * 16 + (tid >> 4);
    int c4 = (tid & 15) * 4;
    float4 v;
    v.x = tile[oc * 65 + c4 + 0];
    v.y = tile[oc * 65 + c4 + 1];
    v.z = tile[oc * 65 + c4 + 2];
    v.w = tile[oc * 65 + c4 + 3];
    *(float4*)(out + ((size_t)(b * 128 + oc)) * 4096 + row * 64 + c4) = v;
  }
}

extern "C" void kernel_launch(void* const* d_in, const int* in_sizes, int n_in,
                              void* d_out, int out_size, void* d_ws, size_t ws_size,
                              hipStream_t stream) {
  const float* x     = (const float*)d_in[0];
  const float* w_off = (const float*)d_in[1];
  const float* b_off = (const float*)d_in[2];
  const float* w_dcn = (const float*)d_in[3];
  const float* b_dcn = (const float*)d_in[4];
  const float* g1    = (const float*)d_in[5];
  const float* bt1   = (const float*)d_in[6];
  const float* w_up  = (const float*)d_in[7];
  const float* g2    = (const float*)d_in[8];
  const float* bt2   = (const float*)d_in[9];
  float* ws  = (float*)d_ws;
  float* out = (float*)d_out;

  prep_xt_kernel<<<5556, 256, 0, stream>>>(x, w_off, w_dcn, w_up, ws);
  offconv_mfma_kernel<<<1024, 256, 0, stream>>>((const __half*)(ws + XT),
                                                (const __half*)(ws + BOFF), ws + OFFB);
  deform_mfma_kernel<<<1024, 256, 0, stream>>>((const __half*)(ws + XT), ws + OFFB, b_off,
                                               (const __half*)(ws + BD), (ushort*)(ws + YP));
  yred_kernel<<<1024, 256, 0, stream>>>((const ushort*)(ws + YP), b_dcn,
                                        (ushort*)(ws + YSUM), ws + ST1);
  ybn_kernel<<<1024, 256, 0, stream>>>((const ushort*)(ws + YSUM), ws + ST1, g1, bt1,
                                       (ushort*)(ws + YBN));
  deconv_mfma_kernel<<<1024, 256, 0, stream>>>((const ushort*)(ws + YBN),
                                               (const ushort*)(ws + BQ),
                                               (ushort*)(ws + OB), ws + ST2);
  bnout_kernel<<<1024, 256, 0, stream>>>((const ushort*)(ws + OB), ws + ST2, g2, bt2, out);
}

// Round 14
// 159.735 us; speedup vs baseline: 1.2287x; 1.0596x over previous
//
#include <hip/hip_runtime.h>
#include <hip/hip_fp16.h>
#include <math.h>

#define HW 1024
#define EPSV 1e-5f

typedef unsigned int uint;
typedef unsigned short ushort;
typedef __attribute__((ext_vector_type(8))) short short8;
typedef __attribute__((ext_vector_type(8))) _Float16 half8;
typedef __attribute__((ext_vector_type(4))) float floatx4;

// ---------------- ws layout (float offsets), no aliasing ---------------------------
static const size_t BOFF = 0;         // 36864 floats = 73728 halves: Boff fragment-major
                                      //   [tap][cs][k2][nh][lane(64)][8]
static const size_t BD   = 36864;     // 147456  fp16 Bd[oc][tap*256+c]
static const size_t BQ   = 184320;    // 131072  bf16 Bq[par][kstep][quad][n][8] (frag order)
static const size_t XT   = 315392;    // 2097152 fp16 xT[b][p][c]
static const size_t OFFB = 2412544;   // 524288  off [b][pix][32] fp32 (atomic-accumulated)
static const size_t ST1  = 2936832;   // 1024: BN1 sum/sq, 4 striped copies of 256
static const size_t ST2  = 2937856;   // 4096: BN2 sum/sq, 16 striped copies of 256
static const size_t YP   = 2941952;   // 4194304 floats = bf16 y_part[4][pix][oc]
static const size_t YSUM = 7136256;   // 1048576 floats = bf16 ysum[pix][oc]
static const size_t YBN  = 8184832;   // (unused after ybn fusion into deconv)
static const size_t OB   = 9233408;   // 4194304 floats = bf16 O[b][par][pix][oc]
// total = 13427712 floats = 53.7 MB

__device__ inline ushort f2bf(float f) {
  uint u = __builtin_bit_cast(uint, f);
  uint r = (u + 0x7FFFu + ((u >> 16) & 1u)) >> 16;
  return (ushort)r;
}
__device__ inline float b2f(ushort u) {
  return __builtin_bit_cast(float, ((uint)u) << 16);
}

// ---------------- 1. prep + xT + zero accumulators & off ---------------------------
// xT blocks pinned so image b lands on XCD b%8 (consistent with all consumers).
__global__ __launch_bounds__(256) void prep_xt_kernel(const float* __restrict__ x,
                                                      const float* __restrict__ w_off,
                                                      const float* __restrict__ w_dcn,
                                                      const float* __restrict__ w_up,
                                                      float* __restrict__ ws) {
  __shared__ float tile[64 * 65];
  int blk = blockIdx.x;
  int tid = threadIdx.x;
  if (blk < 1024) {
    // xT: x[b][c][p] fp32 -> xT[b][p][c] fp16
    int b = blk & 15, pt = (blk >> 4) & 15, cc = blk >> 8;
    int p0 = pt * 64, c0 = cc * 64;
    int pp4 = tid & 15, ci = tid >> 4;    // 16 float4-lanes x 16 rows per iter
#pragma unroll
    for (int it = 0; it < 4; ++it) {
      int c = it * 16 + ci;
      float4 v = *(const float4*)(x + ((size_t)(b * 256 + c0 + c)) * HW + p0 + pp4 * 4);
      tile[c * 65 + pp4 * 4 + 0] = v.x;
      tile[c * 65 + pp4 * 4 + 1] = v.y;
      tile[c * 65 + pp4 * 4 + 2] = v.z;
      tile[c * 65 + pp4 * 4 + 3] = v.w;
    }
    __syncthreads();
    int cp = tid & 31, pp2 = tid >> 5;
    uint* xtu = (uint*)(ws + XT);
#pragma unroll
    for (int it = 0; it < 8; ++it) {
      int p = it * 8 + pp2;
      __half2 h = __floats2half2_rn(tile[(2 * cp) * 65 + p], tile[(2 * cp + 1) * 65 + p]);
      xtu[(size_t)(b * 1024 + p0 + p) * 128 + cc * 32 + cp] = __builtin_bit_cast(uint, h);
    }
  } else if (blk < 3488) {
    int i = (blk - 1024) * 256 + tid;
    if (i < 73728) {
      // Boff fragment-major: [tap][cs][k2][nh][lane][8]
      // element = w_off[n = nh*16+(lane&15)][c = cs*128+k2*32+(lane>>4)*8+j][tap]
      int j = i & 7;
      int lane = (i >> 3) & 63;
      int nh = (i >> 9) & 1;
      int k2 = (i >> 10) & 3;
      int cs = (i >> 12) & 1;
      int tap = i >> 13;
      int n = nh * 16 + (lane & 15);
      int c = cs * 128 + k2 * 32 + (lane >> 4) * 8 + j;
      float v = (n < 27) ? w_off[((size_t)n * 256 + c) * 9 + tap] : 0.f;
      ((__half*)(ws + BOFF))[i] = __float2half(v);
    } else if (i < 73728 + 294912) {
      int d = i - 73728;            // d = oc*2304 + tap*256 + c
      int oc = d / 2304; int k = d % 2304;
      int tap = k >> 8; int c = k & 255;
      ((__half*)(ws + BD))[d] = __float2half(w_dcn[((size_t)oc * 256 + c) * 9 + tap]);
    } else if (i < 73728 + 294912 + 262144) {
      // Bq[par][kstep][quad][n][8] bf16, fragment-ordered for direct global reads
      int d = i - (73728 + 294912);
      int j = d & 7; int n = (d >> 3) & 127; int quad = (d >> 10) & 3;
      int kstep = (d >> 12) & 15; int par = d >> 16;
      int k = kstep * 32 + quad * 8 + j;
      int t4 = k >> 7; int c = k & 127;
      int ty = t4 >> 1, tx = t4 & 1;
      int pu = par >> 1, pv = par & 1;
      int ky = (1 - pu) + 2 * ty, kx = (1 - pv) + 2 * tx;
      float v = w_up[((size_t)c * 128 + n) * 16 + ky * 4 + kx];
      ((ushort*)(ws + BQ))[d] = f2bf(v);
    }
  } else {
    int i = (blk - 3488) * 256 + tid;
    if (i < 5120) ws[ST1 + i] = 0.f;           // ST1(1024)+ST2(4096)
    else if (i < 5120 + 524288) ws[OFFB + (i - 5120)] = 0.f;  // off accumulator
  }
}

// ---------------- 2. offset conv: halo-staged A (1 barrier), frag-major B ----------
// deconv-proven template: stage 3 rows x 34 cols x 128ch coalesced once, tap loop
// from LDS, no per-tap barriers. B read as contiguous 1KB wave loads (L2-resident).
// K-split x2 with atomic accumulate; b pinned via b = blk & 15.
__global__ __launch_bounds__(256) void offconv_mfma_kernel(const __half* __restrict__ xt,
                                                           const __half* __restrict__ bofr,
                                                           float* __restrict__ off) {
  __shared__ short As[102 * 132];   // 26.9 KB
  int blk = blockIdx.x;
  int b = blk & 15, cs = (blk >> 4) & 1, pt = blk >> 5;   // pt 0..31 = h row
  int h = pt;
  int tid = threadIdx.x;
  int wid = tid >> 6, lane = tid & 63, lr = lane & 15, quad = lane >> 4;
  int m_w = (wid & 1) * 16, nh = wid >> 1;
  int n_w = nh * 16;
  const __half* xb = xt + (size_t)b * 1024 * 256 + cs * 128;

  // stage 3 rows x 34 cols x 128 ch, clamped, coalesced (16 lanes = 256B/position)
  for (int idx = tid; idx < 1632; idx += 256) {
    int pos = idx >> 4, seg = idx & 15;
    int r = pos / 34, jj = pos - r * 34;
    int ig = min(max(h - 1 + r, 0), 31);
    int jg = min(max(jj - 1, 0), 31);
    const float4* src = (const float4*)(xb + (size_t)(ig * 32 + jg) * 256 + seg * 8);
    *(float4*)(As + pos * 132 + seg * 8) = *src;
  }
  __syncthreads();

  floatx4 acc = (floatx4)0.f;
  int m = m_w + lr;                 // pixel w-coord 0..31 (A row)
  const __half* bb = bofr + (size_t)lane * 8;
#pragma unroll
  for (int tap = 0; tap < 9; ++tap) {
    int ty = tap / 3, tx = tap % 3;
    bool valid = (h + ty - 1 >= 0) && (h + ty - 1 <= 31) && (m + tx - 1 >= 0) && (m + tx - 1 <= 31);
    int apos = (ty * 34 + m + tx) * 132;
#pragma unroll
    for (int k2 = 0; k2 < 4; ++k2) {
      short8 a = *(const short8*)(As + apos + k2 * 32 + quad * 8);
      short8 az = valid ? a : (short8)0;
      half8 af = __builtin_bit_cast(half8, az);
      half8 bf = *(const half8*)(bb + (size_t)((((tap * 2 + cs) * 4 + k2) * 2) + nh) * 512);
      acc = __builtin_amdgcn_mfma_f32_16x16x32_f16(af, bf, acc, 0, 0, 0);
    }
  }
  int n = n_w + lr;
#pragma unroll
  for (int r = 0; r < 4; ++r) {
    int mm = m_w + quad * 4 + r;
    atomicAdd(&off[((size_t)(b * 1024 + pt * 32 + mm)) * 32 + n], acc[r]);
  }
}

// ---------------- 3. deformable conv: R0 structure + pinning + offset preload ------
// 64-px tiles, 4 waves (2M x 2N), B staged in LDS, 2 barriers/tap.
// b pinned to XCD via b = blk & 15; all 27 offsets preloaded before the loop.
__global__ __launch_bounds__(256) void deform_mfma_kernel(const __half* __restrict__ xt,
                                                          const float* __restrict__ off,
                                                          const float* __restrict__ b_off,
                                                          const __half* __restrict__ bd,
                                                          ushort* __restrict__ y_part) {
  __shared__ short As[64 * 72];
  __shared__ short Bs[128 * 72];
  int blk = blockIdx.x;
  int b = blk & 15;
  int rr = blk >> 4;
  int ptile = rr & 15, cs = rr >> 4;
  int tid = threadIdx.x;
  int wid = tid >> 6, lane = tid & 63, lr = lane & 15, quad = lane >> 4;
  int m_w = (wid & 1) * 32, n_w = (wid >> 1) * 64;
  int P0 = ptile * 64;
  int pix_l = tid >> 2, cseg = tid & 3;   // 64 px x 16-ch segs
  int pix = P0 + pix_l;
  int h = pix >> 5, w = pix & 31;
  const float* offb = off + (size_t)(b * 1024 + pix) * 32;
  const __half* xb = xt + (size_t)b * 1024 * 256 + cs * 64 + cseg * 16;
  int ocb = tid >> 1, seg = tid & 1;      // 128 oc x 32-ch halves
  const __half* bdr = bd + (size_t)ocb * 2304 + cs * 64 + seg * 32;

  // preload all 27 offset floats for this pixel (7 x float4 = 28)
  float4 o4[7];
#pragma unroll
  for (int i = 0; i < 7; ++i) o4[i] = ((const float4*)offb)[i];
  float oflat[28];
#pragma unroll
  for (int i = 0; i < 7; ++i) {
    oflat[4 * i] = o4[i].x; oflat[4 * i + 1] = o4[i].y;
    oflat[4 * i + 2] = o4[i].z; oflat[4 * i + 3] = o4[i].w;
  }

  floatx4 acc[2][4];
#pragma unroll
  for (int mi = 0; mi < 2; ++mi)
#pragma unroll
    for (int ni = 0; ni < 4; ++ni) acc[mi][ni] = (floatx4)0.f;

#pragma unroll
  for (int tap = 0; tap < 9; ++tap) {
    float dy = oflat[2 * tap] + b_off[2 * tap];
    float dx = oflat[2 * tap + 1] + b_off[2 * tap + 1];
    float mraw = oflat[18 + tap] + b_off[18 + tap];
    float mm = 1.f / (1.f + __expf(-mraw));
    float py = (float)(h + tap / 3 - 1) + dy;
    float px = (float)(w + tap % 3 - 1) + dx;
    float y0f = floorf(py), x0f = floorf(px);
    float wy = py - y0f, wx = px - x0f;
    int y0 = (int)y0f, x0 = (int)x0f;
    float cw[4] = {(1.f - wy) * (1.f - wx), (1.f - wy) * wx, wy * (1.f - wx), wy * wx};
    uint4 q[4][2];
    __half2 w2[4];
#pragma unroll
    for (int t = 0; t < 4; ++t) {
      int yy = y0 + (t >> 1), xx = x0 + (t & 1);
      bool v = (yy >= 0) && (yy <= 31) && (xx >= 0) && (xx <= 31);
      int yc = min(max(yy, 0), 31), xc = min(max(xx, 0), 31);
      const uint4* xr = (const uint4*)(xb + (size_t)(yc * 32 + xc) * 256);
      q[t][0] = xr[0]; q[t][1] = xr[1];
      w2[t] = __float2half2_rn(v ? cw[t] * mm : 0.f);
    }
    const float4* gb = (const float4*)(bdr + tap * 256);
    float4 b0 = gb[0], b1 = gb[1], b2 = gb[2], b3 = gb[3];

    __half2 hacc[8];
#pragma unroll
    for (int j = 0; j < 8; ++j) hacc[j] = __float2half2_rn(0.f);
#pragma unroll
    for (int t = 0; t < 4; ++t) {
      uint qa[8] = {q[t][0].x, q[t][0].y, q[t][0].z, q[t][0].w,
                    q[t][1].x, q[t][1].y, q[t][1].z, q[t][1].w};
#pragma unroll
      for (int j = 0; j < 8; ++j)
        hacc[j] = __hfma2(w2[t], __builtin_bit_cast(__half2, qa[j]), hacc[j]);
    }
    if (tap) __syncthreads();
    {
      float4 f0, f1;
      f0.x = __builtin_bit_cast(float, hacc[0]);
      f0.y = __builtin_bit_cast(float, hacc[1]);
      f0.z = __builtin_bit_cast(float, hacc[2]);
      f0.w = __builtin_bit_cast(float, hacc[3]);
      f1.x = __builtin_bit_cast(float, hacc[4]);
      f1.y = __builtin_bit_cast(float, hacc[5]);
      f1.z = __builtin_bit_cast(float, hacc[6]);
      f1.w = __builtin_bit_cast(float, hacc[7]);
      float4* qa2 = (float4*)(As + pix_l * 72 + cseg * 16);
      qa2[0] = f0; qa2[1] = f1;
    }
    float4* qb = (float4*)(Bs + ocb * 72 + seg * 32);
    qb[0] = b0; qb[1] = b1; qb[2] = b2; qb[3] = b3;
    __syncthreads();
#pragma unroll
    for (int k2 = 0; k2 < 2; ++k2) {
      half8 af[2], bf[4];
#pragma unroll
      for (int mi = 0; mi < 2; ++mi)
        af[mi] = *(const half8*)(As + (m_w + mi * 16 + lr) * 72 + k2 * 32 + quad * 8);
#pragma unroll
      for (int ni = 0; ni < 4; ++ni)
        bf[ni] = *(const half8*)(Bs + (n_w + ni * 16 + lr) * 72 + k2 * 32 + quad * 8);
#pragma unroll
      for (int mi = 0; mi < 2; ++mi)
#pragma unroll
        for (int ni = 0; ni < 4; ++ni)
          acc[mi][ni] = __builtin_amdgcn_mfma_f32_16x16x32_f16(af[mi], bf[ni], acc[mi][ni], 0, 0, 0);
    }
  }
  ushort* yp = y_part + (size_t)cs * 2097152 + ((size_t)(b * 1024 + P0)) * 128;
#pragma unroll
  for (int mi = 0; mi < 2; ++mi) {
#pragma unroll
    for (int r = 0; r < 4; ++r) {
      int m = m_w + mi * 16 + quad * 4 + r;
      ushort* orow = yp + (size_t)m * 128;
#pragma unroll
      for (int ni = 0; ni < 4; ++ni)
        orow[n_w + ni * 16 + lr] = f2bf(acc[mi][ni][r]);
    }
  }
}

// ---------------- 4. yred: vectorized, 1024 blocks, XCD-pinned, shfl stats ---------
__global__ __launch_bounds__(256) void yred_kernel(const ushort* __restrict__ yp,
                                                   const float* __restrict__ b_dcn,
                                                   ushort* __restrict__ ysum,
                                                   float* __restrict__ st1) {
  int blk = blockIdx.x;
  int b = blk & 15, seg = blk >> 4;       // 64 segs x 16 px per image
  int tid = threadIdx.x;
  int px = tid >> 4, ocg = tid & 15;      // 16 px x 16 oc-groups (8 ch each)
  int lane = tid & 63, wid = tid >> 6;
  size_t idx = ((size_t)(b * 1024 + seg * 16 + px)) * 128 + ocg * 8;
  short8 p0 = *(const short8*)(yp + idx);
  short8 p1 = *(const short8*)(yp + 2097152 + idx);
  short8 p2 = *(const short8*)(yp + 4194304 + idx);
  short8 p3 = *(const short8*)(yp + 6291456 + idx);
  float s[8], q[8];
  short8 ov;
#pragma unroll
  for (int j = 0; j < 8; ++j) {
    float v = b2f((ushort)p0[j]) + b2f((ushort)p1[j]) + b2f((ushort)p2[j])
            + b2f((ushort)p3[j]) + b_dcn[ocg * 8 + j];
    ov[j] = (short)f2bf(v);
    s[j] = v; q[j] = v * v;
  }
  *(short8*)(ysum + idx) = ov;
#pragma unroll
  for (int j = 0; j < 8; ++j) {
    s[j] += __shfl_xor(s[j], 16); s[j] += __shfl_xor(s[j], 32);
    q[j] += __shfl_xor(q[j], 16); q[j] += __shfl_xor(q[j], 32);
  }
  __shared__ float red[4][256];
  if (lane < 16) {
#pragma unroll
    for (int j = 0; j < 8; ++j) {
      red[wid][lane * 8 + j] = s[j];
      red[wid][128 + lane * 8 + j] = q[j];
    }
  }
  __syncthreads();
  float tot = red[0][tid] + red[1][tid] + red[2][tid] + red[3][tid];
  atomicAdd(&st1[(blk & 3) * 256 + tid], tot);
}

// ---------------- 5. deconv: LDS-staged A with FUSED BN1+ReLU, 2 barriers ----------
// Stage reads ysum, applies BN1+ReLU inline (bit-identical to old ybn's f2bf),
// eliminating the ybn kernel and the 16MB YBN round-trip.
__global__ __launch_bounds__(256) void deconv_mfma_kernel(const ushort* __restrict__ ysum,
                                                          const float* __restrict__ st1,
                                                          const float* __restrict__ g1,
                                                          const float* __restrict__ bt1,
                                                          const ushort* __restrict__ bq,
                                                          ushort* __restrict__ O,
                                                          float* __restrict__ st2) {
  __shared__ short Asd[102 * 132];   // 26.9 KB
  __shared__ float scs[128], shs[128];
  int blk = blockIdx.x;
  int b = blk & 15, par = (blk >> 4) & 3, pt = blk >> 6;   // pt 0..15
  int pu = par >> 1, pv = par & 1;
  int tid = threadIdx.x;
  int wid = tid >> 6, lane = tid & 63, lr = lane & 15, quad = lane >> 4;
  int P0 = pt * 64;
  int h0 = pt * 2;
  const ushort* ysb = ysum + (size_t)b * 1024 * 128;

  if (tid < 128) {
    float s  = st1[tid] + st1[256 + tid] + st1[512 + tid] + st1[768 + tid];
    float sq = st1[128 + tid] + st1[384 + tid] + st1[640 + tid] + st1[896 + tid];
    float mean = s / 16384.f;
    float var = sq / 16384.f - mean * mean;
    float sc = g1[tid] * rsqrtf(var + EPSV);
    scs[tid] = sc;
    shs[tid] = fmaf(-mean, sc, bt1[tid]);
  }
  __syncthreads();

  // stage 3 rows x 34 w-positions x 128 ch with BN1+ReLU applied, coalesced
  for (int idx = tid; idx < 1632; idx += 256) {
    int pos = idx >> 4, seg = idx & 15;
    int r = pos / 34, jj = pos - r * 34;
    int ig = min(max(h0 + pu - 1 + r, 0), 31);
    int jg = min(max(pv - 1 + jj, 0), 31);
    uint4 u = *(const uint4*)(ysb + (size_t)(ig * 32 + jg) * 128 + seg * 8);
    uint words[4] = {u.x, u.y, u.z, u.w};
    uint ow[4];
    int oc0 = seg * 8;
#pragma unroll
    for (int j = 0; j < 4; ++j) {
      ushort u0 = (ushort)(words[j] & 0xFFFFu);
      ushort u1 = (ushort)(words[j] >> 16);
      int c0 = oc0 + 2 * j, c1 = oc0 + 2 * j + 1;
      float v0 = fmaxf(fmaf(b2f(u0), scs[c0], shs[c0]), 0.f);
      float v1 = fmaxf(fmaf(b2f(u1), scs[c1], shs[c1]), 0.f);
      ow[j] = (uint)f2bf(v0) | ((uint)f2bf(v1) << 16);
    }
    uint4 packed = make_uint4(ow[0], ow[1], ow[2], ow[3]);
    *(uint4*)(Asd + pos * 132 + seg * 8) = packed;
  }
  __syncthreads();

  int hh[4], ww[4];
#pragma unroll
  for (int mi = 0; mi < 4; ++mi) {
    int p = P0 + mi * 16 + lr;
    hh[mi] = p >> 5; ww[mi] = p & 31;
  }

  floatx4 acc[4][2];
#pragma unroll
  for (int mi = 0; mi < 4; ++mi)
#pragma unroll
    for (int ni = 0; ni < 2; ++ni) acc[mi][ni] = (floatx4)0.f;

  const ushort* bqb = bq + par * 65536 + quad * 1024 + (wid * 32 + lr) * 8;

#pragma unroll
  for (int tap = 0; tap < 4; ++tap) {
    int ty = tap >> 1, tx = tap & 1;
    int apos[4]; bool val[4];
#pragma unroll
    for (int mi = 0; mi < 4; ++mi) {
      int i = hh[mi] + pu - ty, j = ww[mi] + pv - tx;
      val[mi] = (i >= 0) && (i <= 31) && (j >= 0) && (j <= 31);
      int r = hh[mi] - h0 + 1 - ty;        // 0..2
      int jdx = ww[mi] - tx + 1;           // 0..33
      apos[mi] = (r * 34 + jdx) * 132;
    }
#pragma unroll
    for (int k2 = 0; k2 < 4; ++k2) {
      int kstep = tap * 4 + k2;
      int c0 = k2 * 32 + quad * 8;
      short8 bf[2];
#pragma unroll
      for (int ni = 0; ni < 2; ++ni)
        bf[ni] = *(const short8*)(bqb + kstep * 4096 + ni * 128);
      short8 af[4];
#pragma unroll
      for (int mi = 0; mi < 4; ++mi) {
        short8 a = *(const short8*)(Asd + apos[mi] + c0);
        af[mi] = val[mi] ? a : (short8)0;
      }
#pragma unroll
      for (int mi = 0; mi < 4; ++mi)
#pragma unroll
        for (int ni = 0; ni < 2; ++ni)
          acc[mi][ni] = __builtin_amdgcn_mfma_f32_16x16x32_bf16(af[mi], bf[ni], acc[mi][ni], 0, 0, 0);
    }
  }
  size_t obase = (size_t)(b * 4 + par) * 1024 * 128;
#pragma unroll
  for (int mi = 0; mi < 4; ++mi) {
#pragma unroll
    for (int r = 0; r < 4; ++r) {
      int m = mi * 16 + quad * 4 + r;
      ushort* orow = O + obase + (size_t)(P0 + m) * 128 + wid * 32;
#pragma unroll
      for (int ni = 0; ni < 2; ++ni)
        orow[ni * 16 + lr] = f2bf(acc[mi][ni][r]);
    }
  }
  float sn[2], qn[2];
#pragma unroll
  for (int ni = 0; ni < 2; ++ni) {
    float s = 0.f, q = 0.f;
#pragma unroll
    for (int mi = 0; mi < 4; ++mi)
#pragma unroll
      for (int r = 0; r < 4; ++r) {
        float v = acc[mi][ni][r];
        s += v; q = fmaf(v, v, q);
      }
    sn[ni] = s; qn[ni] = q;
  }
#pragma unroll
  for (int ni = 0; ni < 2; ++ni) {
    sn[ni] += __shfl_xor(sn[ni], 16);
    sn[ni] += __shfl_xor(sn[ni], 32);
    qn[ni] += __shfl_xor(qn[ni], 16);
    qn[ni] += __shfl_xor(qn[ni], 32);
  }
  if (lane < 16) {
    float* dst = st2 + pt * 256;
#pragma unroll
    for (int ni = 0; ni < 2; ++ni) {
      atomicAdd(&dst[wid * 32 + ni * 16 + lr], sn[ni]);
      atomicAdd(&dst[128 + wid * 32 + ni * 16 + lr], qn[ni]);
    }
  }
}

// ---------------- 6. bnout: BN2 + transpose, full-row coalesced stores -------------
// Block = (b, pu, uu): both pv phases -> contiguous float4 out rows.
__global__ __launch_bounds__(256) void bnout_kernel(const ushort* __restrict__ O,
                                                    const float* __restrict__ st2,
                                                    const float* __restrict__ g2,
                                                    const float* __restrict__ bt2,
                                                    float* __restrict__ out) {
  __shared__ float tile[128 * 65];   // 33.3 KB
  __shared__ float scs[128], shs[128];
  int blk = blockIdx.x;
  int b = blk & 15, pu = (blk >> 4) & 1, uu = blk >> 5;   // 16 x 2 x 32 = 1024
  int tid = threadIdx.x;
  if (tid < 128) {
    float s = 0.f, sq = 0.f;
#pragma unroll
    for (int c = 0; c < 16; ++c) {
      s += st2[c * 256 + tid];
      sq += st2[c * 256 + 128 + tid];
    }
    float mean = s / 65536.f;
    float var = sq / 65536.f - mean * mean;
    float sc = g2[tid] * rsqrtf(var + EPSV);
    scs[tid] = sc;
    shs[tid] = fmaf(-mean, sc, bt2[tid]);
  }
  __syncthreads();
  // load both pv slices: 2 x 32 vv x 128 oc, uint2 (4 oc) per thread per iter
#pragma unroll
  for (int it = 0; it < 8; ++it) {
    int linear = it * 256 + tid;          // 0..2047
    int ocg = linear & 31;                 // 4-oc group
    int vv = (linear >> 5) & 31;
    int pv = linear >> 10;                 // 0..1
    const ushort* src = O + ((size_t)(b * 4 + 2 * pu + pv) * 1024 + uu * 32 + vv) * 128 + ocg * 4;
    uint2 u = *(const uint2*)src;
    int col = 2 * vv + pv;
    int oc0 = ocg * 4;
    ushort e0 = (ushort)(u.x & 0xFFFFu), e1 = (ushort)(u.x >> 16);
    ushort e2 = (ushort)(u.y & 0xFFFFu), e3 = (ushort)(u.y >> 16);
    tile[(oc0 + 0) * 65 + col] = fmaxf(fmaf(b2f(e0), scs[oc0 + 0], shs[oc0 + 0]), 0.f);
    tile[(oc0 + 1) * 65 + col] = fmaxf(fmaf(b2f(e1), scs[oc0 + 1], shs[oc0 + 1]), 0.f);
    tile[(oc0 + 2) * 65 + col] = fmaxf(fmaf(b2f(e2), scs[oc0 + 2], shs[oc0 + 2]), 0.f);
    tile[(oc0 + 3) * 65 + col] = fmaxf(fmaf(b2f(e3), scs[oc0 + 3], shs[oc0 + 3]), 0.f);
  }
  __syncthreads();
  // store: full contiguous out rows, float4 per thread; 8 iters cover oc 0..127
  int row = 2 * uu + pu;
#pragma unroll
  for (int it = 0; it < 8; ++it) {
    int oc = it * 16 + (tid >> 4);
    int c4 = (tid & 15) * 4;
    float4 v;
    v.x = tile[oc * 65 + c4 + 0];
    v.y = tile[oc * 65 + c4 + 1];
    v.z = tile[oc * 65 + c4 + 2];
    v.w = tile[oc * 65 + c4 + 3];
    *(float4*)(out + ((size_t)(b * 128 + oc)) * 4096 + row * 64 + c4) = v;
  }
}

extern "C" void kernel_launch(void* const* d_in, const int* in_sizes, int n_in,
                              void* d_out, int out_size, void* d_ws, size_t ws_size,
                              hipStream_t stream) {
  const float* x     = (const float*)d_in[0];
  const float* w_off = (const float*)d_in[1];
  const float* b_off = (const float*)d_in[2];
  const float* w_dcn = (const float*)d_in[3];
  const float* b_dcn = (const float*)d_in[4];
  const float* g1    = (const float*)d_in[5];
  const float* bt1   = (const float*)d_in[6];
  const float* w_up  = (const float*)d_in[7];
  const float* g2    = (const float*)d_in[8];
  const float* bt2   = (const float*)d_in[9];
  float* ws  = (float*)d_ws;
  float* out = (float*)d_out;

  prep_xt_kernel<<<5556, 256, 0, stream>>>(x, w_off, w_dcn, w_up, ws);
  offconv_mfma_kernel<<<1024, 256, 0, stream>>>((const __half*)(ws + XT),
                                                (const __half*)(ws + BOFF), ws + OFFB);
  deform_mfma_kernel<<<1024, 256, 0, stream>>>((const __half*)(ws + XT), ws + OFFB, b_off,
                                               (const __half*)(ws + BD), (ushort*)(ws + YP));
  yred_kernel<<<1024, 256, 0, stream>>>((const ushort*)(ws + YP), b_dcn,
                                        (ushort*)(ws + YSUM), ws + ST1);
  deconv_mfma_kernel<<<1024, 256, 0, stream>>>((const ushort*)(ws + YSUM), ws + ST1, g1, bt1,
                                               (const ushort*)(ws + BQ),
                                               (ushort*)(ws + OB), ws + ST2);
  bnout_kernel<<<1024, 256, 0, stream>>>((const ushort*)(ws + OB), ws + ST2, g2, bt2, out);
}